// Round 6
// baseline (203.547 us; speedup 1.0000x reference)
//
#include <hip/hip_runtime.h>

typedef __attribute__((ext_vector_type(8))) short bf16x8;
typedef __attribute__((ext_vector_type(4))) float f32x4;
typedef unsigned short ushort_t;
typedef unsigned int uint_t;

__device__ __forceinline__ ushort_t f2bf(float f) {
    unsigned int x = __builtin_bit_cast(unsigned int, f);
    x += 0x7fffu + ((x >> 16) & 1u);   // RNE
    return (ushort_t)(x >> 16);
}
// pack two fp32 -> bf16x2 (round-half-up): 2 adds + 1 v_perm
__device__ __forceinline__ uint_t pack2_rn(float a, float b) {
    uint_t au = __builtin_bit_cast(uint_t, a) + 0x8000u;
    uint_t bu = __builtin_bit_cast(uint_t, b) + 0x8000u;
    return __builtin_amdgcn_perm(bu, au, 0x07060302);  // {bu.hi16, au.hi16}
}

#define LOG2E 1.4426950408889634f

// ---------------- workspace layout (ushort elements) ----------------
#define WT_OFF   0
#define WOT_OFF  524288
#define QKV_OFF  655360
#define QKV_SZ   2097152
#define QKV_OFF_Z3 (3 * (size_t)QKV_SZ)
#define O_OFF    9043968

// ---------------- weight transpose + fp32->bf16 (coalesced writes) ----------------
// j<2: Wq/Wq2 scaled by 0.125*log2e (folds attention scale + exp2 conversion)
__global__ __launch_bounds__(256) void transpose_w(
    const float* __restrict__ Wq, const float* __restrict__ Wq2,
    const float* __restrict__ Wk, const float* __restrict__ Wv,
    const float* __restrict__ Wo, ushort_t* __restrict__ ws)
{
    const int j = blockIdx.y;
    const int t = blockIdx.x * 256 + threadIdx.x;   // output flat index
    const float* in;
    ushort_t* out;
    int W;   // output row width = input row count
    if (j < 4) {
        in = (j == 0) ? Wq : (j == 1) ? Wq2 : (j == 2) ? Wk : Wv;
        out = ws + WT_OFF + (size_t)j * 131072;
        W = 512;
    } else {
        in = Wo; out = ws + WOT_OFF; W = 256;
    }
    const int Cin = 131072 / W;
    const float s = (j < 2) ? (0.125f * LOG2E) : 1.0f;
    out[t] = f2bf(in[(size_t)(t % W) * Cin + (t / W)] * s);
}

// ---------------- projections: 64x256 tile per block ----------------
// z: 0: Q=x1@Wq ; 1: Q2=x2@Wq2 ; 2: K=ctx@Wk ; 3: V^T=(ctx@Wv)^T  (scale pre-folded into Wt)
__global__ __launch_bounds__(256) void proj_gemm(
    const float* __restrict__ x1, const float* __restrict__ x2,
    const float* __restrict__ ctx, const ushort_t* __restrict__ Wt,
    ushort_t* __restrict__ QKV)
{
    __shared__ __align__(16) ushort_t lA[64 * 40];
    __shared__ __align__(16) ushort_t lB[256 * 40];
    const int z = blockIdx.y;
    const float* A = (z == 0) ? x1 : (z == 1) ? x2 : ctx;
    const ushort_t* Bt = Wt + (size_t)z * 131072;
    const int tid = threadIdx.x;
    const int wave = tid >> 6, lane = tid & 63;
    const int quad = lane >> 4, l16 = lane & 15;
    const size_t row0 = (size_t)blockIdx.x * 64;
    const int sr = tid >> 2, sc8 = (tid & 3) << 3;

    f32x4 acc[16] = {};
    for (int k0 = 0; k0 < 512; k0 += 32) {
        const float* src = A + (row0 + sr) * 512 + k0 + sc8;
        float4 v0 = *(const float4*)src;
        float4 v1 = *(const float4*)(src + 4);
        uint4 packed;
        packed.x = pack2_rn(v0.x, v0.y);
        packed.y = pack2_rn(v0.z, v0.w);
        packed.z = pack2_rn(v1.x, v1.y);
        packed.w = pack2_rn(v1.z, v1.w);
        *(uint4*)&lA[sr * 40 + sc8] = packed;
#pragma unroll
        for (int rr = 0; rr < 4; ++rr)
            *(uint4*)&lB[(rr * 64 + sr) * 40 + sc8] =
                *(const uint4*)(Bt + (size_t)(rr * 64 + sr) * 512 + k0 + sc8);
        __syncthreads();
        bf16x8 af = *(const bf16x8*)&lA[(wave * 16 + l16) * 40 + quad * 8];
        if (z == 3) {
#pragma unroll
            for (int c = 0; c < 16; ++c) {
                bf16x8 bfr = *(const bf16x8*)&lB[(c * 16 + l16) * 40 + quad * 8];
                acc[c] = __builtin_amdgcn_mfma_f32_16x16x32_bf16(af, bfr, acc[c], 0, 0, 0);
            }
        } else {
            // swapped operands: C^T, lane regs = 4 consecutive out-cols
#pragma unroll
            for (int c = 0; c < 16; ++c) {
                bf16x8 bfr = *(const bf16x8*)&lB[(c * 16 + l16) * 40 + quad * 8];
                acc[c] = __builtin_amdgcn_mfma_f32_16x16x32_bf16(bfr, af, acc[c], 0, 0, 0);
            }
        }
        __syncthreads();
    }
    if (z == 3) {
        // V^T store: Vt[(b*4+h)*64 + d][tok]; regs = 4 consecutive tokens
        const int b = (int)(row0 >> 11);
        const int tokl = ((int)row0 & 2047) + wave * 16 + quad * 4;
        ushort_t* Vt = QKV + QKV_OFF_Z3;
#pragma unroll
        for (int c = 0; c < 16; ++c) {
            const int col = c * 16 + l16;
            const int h = col >> 6, d = col & 63;
            uint2 w;
            w.x = pack2_rn(acc[c][0], acc[c][1]);
            w.y = pack2_rn(acc[c][2], acc[c][3]);
            *(uint2*)(Vt + ((size_t)((b * 4 + h) * 64 + d)) * 2048 + tokl) = w;
        }
    } else {
        ushort_t* C = QKV + (size_t)z * QKV_SZ;
        const size_t tok = row0 + wave * 16 + l16;
#pragma unroll
        for (int c = 0; c < 16; ++c) {
            uint2 w;
            w.x = pack2_rn(acc[c][0], acc[c][1]);
            w.y = pack2_rn(acc[c][2], acc[c][3]);
            *(uint2*)(C + tok * 256 + c * 16 + quad * 4) = w;
        }
    }
}

// ---------------- output projection: 64x256 tile, C^T orientation ----------------
__global__ __launch_bounds__(256) void out_gemm(
    const ushort_t* __restrict__ Op, const ushort_t* __restrict__ Wot,
    const float* __restrict__ bias, float* __restrict__ out)
{
    __shared__ __align__(16) ushort_t lA[64 * 40];
    __shared__ __align__(16) ushort_t lB[256 * 40];
    const int tid = threadIdx.x;
    const int wave = tid >> 6, lane = tid & 63;
    const int quad = lane >> 4, l16 = lane & 15;
    const size_t row0 = (size_t)blockIdx.x * 64;
    const int col0 = blockIdx.y * 256;
    const int sr = tid >> 2, sc8 = (tid & 3) << 3;

    f32x4 acc[16] = {};
    for (int k0 = 0; k0 < 256; k0 += 32) {
        *(uint4*)&lA[sr * 40 + sc8] = *(const uint4*)(Op + (row0 + sr) * 256 + k0 + sc8);
#pragma unroll
        for (int rr = 0; rr < 4; ++rr)
            *(uint4*)&lB[(rr * 64 + sr) * 40 + sc8] =
                *(const uint4*)(Wot + (size_t)(col0 + rr * 64 + sr) * 256 + k0 + sc8);
        __syncthreads();
        bf16x8 af = *(const bf16x8*)&lA[(wave * 16 + l16) * 40 + quad * 8];
#pragma unroll
        for (int c = 0; c < 16; ++c) {
            bf16x8 bfr = *(const bf16x8*)&lB[(c * 16 + l16) * 40 + quad * 8];
            acc[c] = __builtin_amdgcn_mfma_f32_16x16x32_bf16(bfr, af, acc[c], 0, 0, 0);
        }
        __syncthreads();
    }
    const size_t tok = row0 + wave * 16 + l16;
#pragma unroll
    for (int c = 0; c < 16; ++c) {
        const int col = col0 + c * 16 + quad * 4;
        const float4 bv = *(const float4*)&bias[col];
        float4 o;
        o.x = acc[c][0] + bv.x; o.y = acc[c][1] + bv.y;
        o.z = acc[c][2] + bv.z; o.w = acc[c][3] + bv.w;
        *(float4*)&out[tok * 512 + col] = o;
    }
}

// ---------------- fused dual-softmax flash attention ----------------
// S^T = K·Q^T, static-max (p = exp2(s) raw), O^T = V^T·P^T.
// K LDS: [ktok][64 d], 16B-groups XOR-swizzled by ktok&7.
// V^T LDS: [d][64 tok], groups XOR-swizzled by d&7 (same formula).

#define ATTN_STAGE(MB, BUF) do {                                                        \
    _Pragma("unroll")                                                                   \
    for (int it_ = 0; it_ < 2; ++it_) {                                                 \
        const int cc_ = tid + it_ * 256;                                                \
        const int g_ = (cc_ ^ (cc_ >> 3)) & 7;                                          \
        const ushort_t* kp_ = Kb + (size_t)(tok0 + (MB) + (cc_ >> 3)) * 256 + in0 + g_ * 8; \
        __builtin_amdgcn_global_load_lds(                                               \
            (const __attribute__((address_space(1))) void*)kp_,                         \
            (__attribute__((address_space(3))) void*)&lK[BUF][cc_ * 8], 16, 0, 0);      \
        const ushort_t* vp_ = Vt + (size_t)(bh64 + (cc_ >> 3)) * 2048 + (MB) + g_ * 8;  \
        __builtin_amdgcn_global_load_lds(                                               \
            (const __attribute__((address_space(1))) void*)vp_,                         \
            (__attribute__((address_space(3))) void*)&lV[BUF][cc_ * 8], 16, 0, 0);      \
    }                                                                                   \
} while (0)

#define ATTN_ITER(I, P) do {                                                            \
    __syncthreads();                                                                    \
    { const int mn_ = ((I) + 1) * 64; if (mn_ < 2048) ATTN_STAGE(mn_, 1 - (P)); }       \
    f32x4 st1[4] = {}, st2[4] = {};                                                     \
    _Pragma("unroll")                                                                   \
    for (int c = 0; c < 4; ++c) {                                                       \
        _Pragma("unroll")                                                               \
        for (int ks = 0; ks < 2; ++ks) {                                                \
            bf16x8 kf = *(const bf16x8*)&lK[P][(c * 16 + l16) * 64 +                    \
                                              ((((ks * 4 + quad) ^ l7) & 7) << 3)];     \
            st1[c] = __builtin_amdgcn_mfma_f32_16x16x32_bf16(kf, q1f[ks], st1[c], 0, 0, 0); \
            st2[c] = __builtin_amdgcn_mfma_f32_16x16x32_bf16(kf, q2f[ks], st2[c], 0, 0, 0); \
        } }                                                                             \
    _Pragma("unroll")                                                                   \
    for (int c = 0; c < 4; ++c) {                                                       \
        float p0 = __builtin_amdgcn_exp2f(st1[c][0]);                                   \
        float p1 = __builtin_amdgcn_exp2f(st1[c][1]);                                   \
        float p2 = __builtin_amdgcn_exp2f(st1[c][2]);                                   \
        float p3 = __builtin_amdgcn_exp2f(st1[c][3]);                                   \
        l1 += (p0 + p1) + (p2 + p3);                                                    \
        uint2 w; w.x = pack2_rn(p0, p1); w.y = pack2_rn(p2, p3);                        \
        *(uint2*)&lPw0[l16 * 72 + c * 16 + quad * 4] = w;                               \
        float r0 = __builtin_amdgcn_exp2f(st2[c][0]);                                   \
        float r1 = __builtin_amdgcn_exp2f(st2[c][1]);                                   \
        float r2 = __builtin_amdgcn_exp2f(st2[c][2]);                                   \
        float r3 = __builtin_amdgcn_exp2f(st2[c][3]);                                   \
        l2 += (r0 + r1) + (r2 + r3);                                                    \
        uint2 y; y.x = pack2_rn(r0, r1); y.y = pack2_rn(r2, r3);                        \
        *(uint2*)&lPw1[l16 * 72 + c * 16 + quad * 4] = y;                               \
    }                                                                                   \
    bf16x8 pa1[2], pa2[2];                                                              \
    _Pragma("unroll")                                                                   \
    for (int ks = 0; ks < 2; ++ks) {                                                    \
        pa1[ks] = *(const bf16x8*)&lPw0[l16 * 72 + ks * 32 + quad * 8];                 \
        pa2[ks] = *(const bf16x8*)&lPw1[l16 * 72 + ks * 32 + quad * 8];                 \
    }                                                                                   \
    _Pragma("unroll")                                                                   \
    for (int c = 0; c < 4; ++c) {                                                       \
        _Pragma("unroll")                                                               \
        for (int ks = 0; ks < 2; ++ks) {                                                \
            bf16x8 vf = *(const bf16x8*)&lV[P][(c * 16 + l16) * 64 +                    \
                                              ((((ks * 4 + quad) ^ l7) & 7) << 3)];     \
            o1[c] = __builtin_amdgcn_mfma_f32_16x16x32_bf16(vf, pa1[ks], o1[c], 0, 0, 0); \
            o2[c] = __builtin_amdgcn_mfma_f32_16x16x32_bf16(vf, pa2[ks], o2[c], 0, 0, 0); \
        } }                                                                             \
} while (0)

__global__ __launch_bounds__(256) void attn_fused(
    const ushort_t* __restrict__ Qb, const ushort_t* __restrict__ Q2b,
    const ushort_t* __restrict__ Kb, const ushort_t* __restrict__ Vt,
    ushort_t* __restrict__ Ob)
{
    __shared__ __align__(16) ushort_t lK[2][64 * 64];
    __shared__ __align__(16) ushort_t lV[2][64 * 64];
    __shared__ __align__(16) ushort_t lP[4][2][16 * 72];

    const int qt = blockIdx.x;
    const int bh = blockIdx.y;
    const int tid = threadIdx.x;
    const int wave = tid >> 6, lane = tid & 63;
    const int quad = lane >> 4, l16 = lane & 15;
    const int l7 = l16 & 7;
    const size_t tok0 = (size_t)(bh >> 2) * 2048;
    const int in0 = (bh & 3) * 64;
    const int bh64 = bh * 64;
    ushort_t* lPw0 = &lP[wave][0][0];
    ushort_t* lPw1 = &lP[wave][1][0];

    // Q fragments: direct global load (B-operand layout is row-contiguous 16B)
    bf16x8 q1f[2], q2f[2];
    {
        const ushort_t* qr1 = Qb  + (tok0 + qt * 64 + wave * 16 + l16) * 256 + in0;
        const ushort_t* qr2 = Q2b + (tok0 + qt * 64 + wave * 16 + l16) * 256 + in0;
#pragma unroll
        for (int ks = 0; ks < 2; ++ks) {
            q1f[ks] = *(const bf16x8*)(qr1 + ks * 32 + quad * 8);
            q2f[ks] = *(const bf16x8*)(qr2 + ks * 32 + quad * 8);
        }
    }

    ATTN_STAGE(0, 0);

    f32x4 o1[4] = {}, o2[4] = {};
    float l1 = 0.f, l2 = 0.f;

    for (int i = 0; i < 32; i += 2) {
        ATTN_ITER(i, 0);
        ATTN_ITER(i + 1, 1);
    }

    // l reduction across quads (lanes with same l16)
    l1 += __shfl_xor(l1, 16, 64); l1 += __shfl_xor(l1, 32, 64);
    l2 += __shfl_xor(l2, 16, 64); l2 += __shfl_xor(l2, 32, 64);
    const float inv1 = 0.3f / l1, inv2 = 0.7f / l2;

    // O^T C-layout: row d = c*16 + quad*4 + r, col q = l16
    ushort_t* orow = Ob + (tok0 + qt * 64 + wave * 16 + l16) * 256 + in0;
#pragma unroll
    for (int c = 0; c < 4; ++c) {
        const float f0 = o1[c][0] * inv1 + o2[c][0] * inv2;
        const float f1 = o1[c][1] * inv1 + o2[c][1] * inv2;
        const float f2 = o1[c][2] * inv1 + o2[c][2] * inv2;
        const float f3 = o1[c][3] * inv1 + o2[c][3] * inv2;
        uint2 w; w.x = pack2_rn(f0, f1); w.y = pack2_rn(f2, f3);
        *(uint2*)(orow + c * 16 + quad * 4) = w;
    }
}

// ---------------- launch ----------------
extern "C" void kernel_launch(void* const* d_in, const int* in_sizes, int n_in,
                              void* d_out, int out_size, void* d_ws, size_t ws_size,
                              hipStream_t stream)
{
    (void)in_sizes; (void)n_in; (void)out_size; (void)ws_size;
    const float* x1  = (const float*)d_in[0];
    const float* x2  = (const float*)d_in[1];
    const float* ctx = (const float*)d_in[2];
    const float* Wq  = (const float*)d_in[3];
    const float* Wq2 = (const float*)d_in[4];
    const float* Wk  = (const float*)d_in[5];
    const float* Wv  = (const float*)d_in[6];
    const float* Wo  = (const float*)d_in[7];
    const float* bo  = (const float*)d_in[8];
    ushort_t* ws  = (ushort_t*)d_ws;
    float* out = (float*)d_out;

    ushort_t* Wt  = ws + WT_OFF;
    ushort_t* Wot = ws + WOT_OFF;
    ushort_t* QKV = ws + QKV_OFF;
    ushort_t* Q   = QKV;
    ushort_t* Q2  = QKV + 1 * (size_t)QKV_SZ;
    ushort_t* Kp  = QKV + 2 * (size_t)QKV_SZ;
    ushort_t* Vt  = QKV + 3 * (size_t)QKV_SZ;
    ushort_t* Op  = ws + O_OFF;

    transpose_w<<<dim3(512, 5), 256, 0, stream>>>(Wq, Wq2, Wk, Wv, Wo, ws);
    proj_gemm  <<<dim3(128, 4), 256, 0, stream>>>(x1, x2, ctx, Wt, QKV);
    attn_fused <<<dim3(32, 16), 256, 0, stream>>>(Q, Q2, Kp, Vt, Op);
    out_gemm   <<<dim3(128, 2), 256, 0, stream>>>(Op, Wot, bo, out);
}